// Round 12
// baseline (492.042 us; speedup 1.0000x reference)
//
#include <hip/hip_runtime.h>
#include <hip/hip_bf16.h>

#define N_NODES 40000
#define N_EDGES 480000
#define SEG 2
#define SEG_E (N_EDGES / SEG)      // 240000
#define SEG_TILES (SEG_E / 16)     // 15000
#define SCAN_BLOCKS 157            // ceil(40000/256)
#define TPW 4                      // tiles per wave in mlp_kernel (best measured)

typedef short bf16x8 __attribute__((ext_vector_type(8)));
typedef float f32x4 __attribute__((ext_vector_type(4)));

__device__ __forceinline__ float bf2f(__hip_bfloat16 x) { return __bfloat162float(x); }

__device__ __forceinline__ float swishf(float x) { return x / (1.0f + __expf(-x)); }

__device__ __forceinline__ float bflo(unsigned u) { union { unsigned u; float f; } w; w.u = u << 16; return w.f; }
__device__ __forceinline__ float bfhi(unsigned u) { union { unsigned u; float f; } w; w.u = u & 0xffff0000u; return w.f; }
__device__ __forceinline__ float bfu(unsigned short u) { union { unsigned u; float f; } w; w.u = ((unsigned)u) << 16; return w.f; }

__device__ __forceinline__ unsigned short f2bf_bits(float x) {
    union { __hip_bfloat16 h; unsigned short u; } c; c.h = __float2bfloat16(x); return c.u;
}

__constant__ const float INV8 = 0.35355339059327373f;
__constant__ const float INV64 = 0.125f;
__constant__ const float INV128 = 0.08838834764831845f;
__constant__ const float INV_NN = 0.2886751345948129f;   // 1/sqrt(12)
__constant__ const float SQRT2 = 1.4142135623730951f;
__constant__ const float SQRT3 = 1.7320508075688772f;
__constant__ const float INV_SQRT3 = 0.5773502691896258f;
__constant__ const float PI_F = 3.14159265358979323846f;

// runtime-dtype load: flag==0 => f32 inputs; flag!=0 => bf16 inputs.
__device__ __forceinline__ float LDf(const void* p, size_t i, bool f32) {
    float v;
    if (f32) v = ((const float*)p)[i];
    else     v = bf2f(((const __hip_bfloat16*)p)[i]);
    return v;
}
// load 8 consecutive elements as float (16B-aligned in both dtype paths)
__device__ __forceinline__ void load_f8r(const void* p, size_t i, bool f32, float* out) {
    if (f32) {
        const float4* q4 = (const float4*)((const float*)p + i);
        float4 a = q4[0], b = q4[1];
        out[0] = a.x; out[1] = a.y; out[2] = a.z; out[3] = a.w;
        out[4] = b.x; out[5] = b.y; out[6] = b.z; out[7] = b.w;
    } else {
        bf16x8 v = *(const bf16x8*)((const unsigned short*)p + i);
        #pragma unroll
        for (int j = 0; j < 8; j++) out[j] = bfu((unsigned short)v[j]);
    }
}

// ---------------- dtype probe ----------------
// flag = 1 iff weight buffer looks like bf16 (every 16-bit word has a sane exponent field)
__global__ void detect_kernel(const unsigned short* __restrict__ w, int* __restrict__ flag) {
    int lane = threadIdx.x;
    int cnt = 0;
    for (int i = lane; i < 2048; i += 64) {
        unsigned e = (w[2 * i] >> 7) & 0xFF;
        if (e >= 110 && e <= 133) cnt++;
    }
    #pragma unroll
    for (int off = 32; off > 0; off >>= 1) cnt += __shfl_down(cnt, off, 64);
    if (lane == 0) *flag = (cnt > 1024) ? 1 : 0;
}

// ---------------- weight pre-conversion (once): f32/bf16 -> bf16 LDS-image layouts ----------------
// Weight images that are read from LDS as bf16x8 fragments are XOR-SWIZZLED in 16B
// groups: group c of row r stored at (c ^ (r&7)).  Bank index becomes
// 4m + 4(c^(m&7)) mod 32 -> exactly 2 lanes/bank (free) instead of 8-way conflicts.
__global__ __launch_bounds__(256) void wprep_kernel(
    const void* __restrict__ W_up_s, const void* __restrict__ W_up_v,
    const void* __restrict__ W_skip_s, const void* __restrict__ W_skip_v,
    const void* __restrict__ W_down_s, const void* __restrict__ W_down_v,
    const void* __restrict__ W_mlp2, const void* __restrict__ W_mlp3,
    unsigned short* __restrict__ Wup_sq, unsigned short* __restrict__ Wup_vq,
    unsigned short* __restrict__ Wq_s, unsigned short* __restrict__ Wq_v,
    unsigned short* __restrict__ W2q, unsigned short* __restrict__ W3q,
    const int* __restrict__ flag)
{
    bool f32 = (*flag == 0);
    const float SC = INV128 * INV_NN;
    int gid = blockIdx.x * 256 + threadIdx.x;
    int gs = gridDim.x * 256;
    // node_up weights: [o][k], stride 72, *INV64, swizzled k-groups
    for (int i = gid; i < 4096; i += gs) {
        int o = i & 63, k = i >> 6;
        int kk = (((k >> 3) ^ (o & 7)) << 3) | (k & 7);
        Wup_sq[o * 72 + kk] = f2bf_bits(LDf(W_up_s, k * 64 + o, f32) * INV64);
        Wup_vq[o * 72 + kk] = f2bf_bits(LDf(W_up_v, k * 64 + o, f32) * INV64);
    }
    // node_final As: per-species [128][200], k<192, swizzled
    for (int i = gid; i < 5 * 128 * 192; i += gs) {
        int sp = i / 24576, r = i - sp * 24576;
        int o = r / 192, k = r - o * 192;
        float w = (k < 128) ? LDf(W_down_s, k * 128 + o, f32) * SC
                            : LDf(W_skip_s, sp * 8192 + (k - 128) * 128 + o, f32) * INV64;
        int kk = (((k >> 3) ^ (o & 7)) << 3) | (k & 7);
        Wq_s[sp * 25600 + o * 200 + kk] = f2bf_bits(w);
    }
    // node_final Av: per-species [64][200], k<192, swizzled
    for (int i = gid; i < 5 * 64 * 192; i += gs) {
        int sp = i / 12288, r = i - sp * 12288;
        int o = r / 192, k = r - o * 192;
        float w = (k < 128) ? LDf(W_down_v, k * 64 + o, f32) * SC
                            : LDf(W_skip_v, sp * 4096 + (k - 128) * 64 + o, f32) * INV64;
        int kk = (((k >> 3) ^ (o & 7)) << 3) | (k & 7);
        Wq_v[sp * 12800 + o * 200 + kk] = f2bf_bits(w);
    }
    // mlp W3T: [256][72], swizzled
    for (int i = gid; i < 16384; i += gs) {
        int o = i & 255, k = i >> 8;
        int kk = (((k >> 3) ^ (o & 7)) << 3) | (k & 7);
        W3q[o * 72 + kk] = f2bf_bits(LDf(W_mlp3, k * 256 + o, f32));
    }
    // mlp W2T: [64][72], NOT swizzled (read straight to registers from global)
    for (int i = gid; i < 4096; i += gs) {
        int o = i & 63, k = i >> 6;
        W2q[o * 72 + k] = f2bf_bits(LDf(W_mlp2, k * 64 + o, f32));
    }
}

// ---------------- counting sort of edges by receiver ----------------
__global__ __launch_bounds__(256) void hist_kernel(const int* __restrict__ receivers,
                                                   int* __restrict__ cnt) {
    int e = blockIdx.x * 256 + threadIdx.x;
    if (e < N_EDGES) atomicAdd(&cnt[receivers[e]], 1);
}

__global__ __launch_bounds__(256) void partial_kernel(const int* __restrict__ cnt,
                                                      int* __restrict__ partials) {
    __shared__ int red[4];
    int idx = blockIdx.x * 256 + threadIdx.x;
    int v = (idx < N_NODES) ? cnt[idx] : 0;
    #pragma unroll
    for (int off = 32; off > 0; off >>= 1) v += __shfl_down(v, off, 64);
    int wave = threadIdx.x >> 6, lane = threadIdx.x & 63;
    if (lane == 0) red[wave] = v;
    __syncthreads();
    if (threadIdx.x == 0) partials[blockIdx.x] = red[0] + red[1] + red[2] + red[3];
}

__global__ __launch_bounds__(256) void scanp_kernel(const int* __restrict__ partials,
                                                    int* __restrict__ pscan) {
    __shared__ int buf[256];
    int t = threadIdx.x;
    int v = (t < SCAN_BLOCKS) ? partials[t] : 0;
    buf[t] = v;
    __syncthreads();
    for (int off = 1; off < 256; off <<= 1) {
        int tmp = (t >= off) ? buf[t - off] : 0;
        __syncthreads();
        buf[t] += tmp;
        __syncthreads();
    }
    if (t < SCAN_BLOCKS) pscan[t] = buf[t] - v;   // exclusive
}

__global__ __launch_bounds__(256) void offs_kernel(const int* __restrict__ cnt,
                                                   const int* __restrict__ pscan,
                                                   int* __restrict__ offs,
                                                   int* __restrict__ cursor) {
    __shared__ int buf[256];
    int b = blockIdx.x, t = threadIdx.x;
    int idx = b * 256 + t;
    int v = (idx < N_NODES) ? cnt[idx] : 0;
    buf[t] = v;
    __syncthreads();
    for (int off = 1; off < 256; off <<= 1) {
        int tmp = (t >= off) ? buf[t - off] : 0;
        __syncthreads();
        buf[t] += tmp;
        __syncthreads();
    }
    int exc = buf[t] - v + pscan[b];
    if (idx < N_NODES) { offs[idx] = exc; cursor[idx] = exc; }
    if (idx == N_NODES - 1) offs[N_NODES] = exc + v;
}

// scatter: sort senders by receiver AND pre-compute ALL per-edge geometry:
// Y (sph harmonics, bf16 yq) and radial basis rb[8] (bf16x8 rbq), in sorted order.
__global__ __launch_bounds__(256) void scatter_kernel(const int* __restrict__ receivers,
                                                      const int* __restrict__ senders,
                                                      const void* __restrict__ vectors,
                                                      int* __restrict__ cursor,
                                                      int* __restrict__ sorted_snd,
                                                      unsigned short* __restrict__ yq,
                                                      unsigned short* __restrict__ rbq,
                                                      const int* __restrict__ flag) {
    bool f32 = (*flag == 0);
    int e = blockIdx.x * 256 + threadIdx.x;
    if (e < N_EDGES) {
        float vx = LDf(vectors, (size_t)e * 3 + 0, f32);
        float vy = LDf(vectors, (size_t)e * 3 + 1, f32);
        float vz = LDf(vectors, (size_t)e * 3 + 2, f32);
        float len2 = vx * vx + vy * vy + vz * vz;
        float len = sqrtf(len2);
        float Yx = 0.f, Yy = 0.f, Yz = 0.f;
        float rb[8];
        if (len > 0.f) {
            float inv = 1.f / len;
            Yx = SQRT3 * vx * inv; Yy = SQRT3 * vy * inv; Yz = SQRT3 * vz * inv;
            float x6 = len2 * len2 * len2;
            float env = (len < 1.f) ? fmaf(x6, fmaf(len, fmaf(len, -21.f, 48.f), -28.f), 1.f) : 0.f;
            float c = SQRT2 * inv * env;
            #pragma unroll
            for (int k = 0; k < 8; k++) rb[k] = c * __sinf((float)(k + 1) * PI_F * len);
        } else {
            #pragma unroll
            for (int k = 0; k < 8; k++) rb[k] = 0.f;
        }
        int p = atomicAdd(&cursor[receivers[e]], 1);
        sorted_snd[p] = senders[e];
        uint2 yw;
        yw.x = f2bf_bits(Yx) | ((unsigned)f2bf_bits(Yy) << 16);
        yw.y = f2bf_bits(Yz);
        *(uint2*)(yq + (size_t)p * 4) = yw;
        bf16x8 r8;
        #pragma unroll
        for (int k = 0; k < 8; k++) r8[k] = (short)f2bf_bits(rb[k]);
        *(bf16x8*)(rbq + (size_t)p * 8) = r8;
    }
}

// ---------------- counting sort of nodes by species ----------------
__global__ __launch_bounds__(256) void hist5_kernel(const int* __restrict__ specie,
                                                    int* __restrict__ cnt5) {
    int n = blockIdx.x * 256 + threadIdx.x;
    int lane = threadIdx.x & 63;
    int sp = (n < N_NODES) ? specie[n] : -1;
    #pragma unroll
    for (int s = 0; s < 5; s++) {
        unsigned long long mask = __ballot(sp == s);
        if (mask != 0ull) {
            int leader = __builtin_ctzll(mask);
            if (lane == leader) atomicAdd(&cnt5[s], __popcll(mask));
        }
    }
}

__global__ void scan5_kernel(const int* __restrict__ cnt5, int* __restrict__ sp_offs,
                             int* __restrict__ cursor5, int* __restrict__ tile_info) {
    if (threadIdx.x != 0 || blockIdx.x != 0) return;
    int run = 0, tb = 0;
    for (int s = 0; s < 5; s++) {
        sp_offs[s] = run; cursor5[s] = run;
        tile_info[s] = tb;
        int c = cnt5[s];
        int T = (c + 15) >> 4;
        tile_info[8 + s] = T;
        tb += (T + 3) >> 2;
        run += c;
    }
    sp_offs[5] = run;
    tile_info[5] = tb;
}

__global__ __launch_bounds__(256) void scatter5_kernel(const int* __restrict__ specie,
                                                       int* __restrict__ cursor5,
                                                       int* __restrict__ sorted_node) {
    int n = blockIdx.x * 256 + threadIdx.x;
    int lane = threadIdx.x & 63;
    int sp = (n < N_NODES) ? specie[n] : -1;
    #pragma unroll
    for (int s = 0; s < 5; s++) {
        unsigned long long mask = __ballot(sp == s);
        if (mask != 0ull) {
            int leader = __builtin_ctzll(mask);
            int base = 0;
            if (lane == leader) base = atomicAdd(&cursor5[s], __popcll(mask));
            base = __shfl(base, leader);
            if (sp == s) {
                int prefix = __popcll(mask & ((1ull << lane) - 1ull));
                sorted_node[base + prefix] = n;
            }
        }
    }
}

// ---------------- Kernel A: per-node up-projection via MFMA (+ bf16 input packing) ----------------
__global__ __launch_bounds__(256) void node_up_kernel(
    const void* __restrict__ node_scalars,
    const void* __restrict__ node_vectors,
    const unsigned short* __restrict__ Wup_sq,
    const unsigned short* __restrict__ Wup_vq,
    unsigned short* __restrict__ hbuf,
    unsigned short* __restrict__ ns_b,
    unsigned short* __restrict__ nv_t,
    const int* __restrict__ flag)
{
    bool f32 = (*flag == 0);
    __shared__ __align__(16) unsigned short WsT[64 * 72];   // [o][k-swz], *INV64 folded
    __shared__ __align__(16) unsigned short WvT[64 * 72];
    int tid = threadIdx.x;
    for (int i = tid; i < 576; i += 256) {                  // verbatim copy (swizzle baked in)
        ((uint4*)WsT)[i] = ((const uint4*)Wup_sq)[i];
        ((uint4*)WvT)[i] = ((const uint4*)Wup_vq)[i];
    }
    __syncthreads();
    int wave = tid >> 6, lane = tid & 63;
    int m = lane & 15, q = lane >> 4;
    int base = (blockIdx.x * 4 + wave) * 16;         // 16 nodes per wave; 625 blocks * 64 = 40000

    f32x4 accS[4];
    f32x4 accV[3][4];
    #pragma unroll
    for (int t = 0; t < 4; t++) {
        accS[t] = f32x4{0.f, 0.f, 0.f, 0.f};
        #pragma unroll
        for (int c = 0; c < 3; c++) accV[c][t] = f32x4{0.f, 0.f, 0.f, 0.f};
    }

    #pragma unroll
    for (int kk = 0; kk < 2; kk++) {
        int i0 = kk * 32 + 8 * q;                    // k-slice this lane owns
        float fs[8];
        load_f8r(node_scalars, (size_t)(base + m) * 64 + i0, f32, fs);
        bf16x8 aS;
        #pragma unroll
        for (int j = 0; j < 8; j++) aS[j] = (short)f2bf_bits(fs[j]);
        *(bf16x8*)(ns_b + (size_t)(base + m) * 64 + i0) = aS;
        float fv[24];
        size_t vbase = (size_t)(base + m) * 192 + (size_t)i0 * 3;
        load_f8r(node_vectors, vbase,      f32, fv);
        load_f8r(node_vectors, vbase + 8,  f32, fv + 8);
        load_f8r(node_vectors, vbase + 16, f32, fv + 16);
        bf16x8 aV[3];
        #pragma unroll
        for (int c = 0; c < 3; c++) {
            #pragma unroll
            for (int j = 0; j < 8; j++) aV[c][j] = (short)f2bf_bits(fv[3 * j + c]);
            *(bf16x8*)(nv_t + (size_t)c * N_NODES * 64 + (size_t)(base + m) * 64 + i0) = aV[c];
        }
        #pragma unroll
        for (int t = 0; t < 4; t++) {
            int g = ((4 * kk + q) ^ (m & 7)) << 3;   // swizzled 16B group
            bf16x8 bS = *(const bf16x8*)(WsT + (16 * t + m) * 72 + g);
            bf16x8 bV = *(const bf16x8*)(WvT + (16 * t + m) * 72 + g);
            accS[t]    = __builtin_amdgcn_mfma_f32_16x16x32_bf16(aS,    bS, accS[t],    0, 0, 0);
            accV[0][t] = __builtin_amdgcn_mfma_f32_16x16x32_bf16(aV[0], bV, accV[0][t], 0, 0, 0);
            accV[1][t] = __builtin_amdgcn_mfma_f32_16x16x32_bf16(aV[1], bV, accV[1][t], 0, 0, 0);
            accV[2][t] = __builtin_amdgcn_mfma_f32_16x16x32_bf16(aV[2], bV, accV[2][t], 0, 0, 0);
        }
    }
    #pragma unroll
    for (int t = 0; t < 4; t++) {
        #pragma unroll
        for (int r = 0; r < 4; r++) {
            uint2 pk;
            pk.x = (unsigned)f2bf_bits(accS[t][r])    | ((unsigned)f2bf_bits(accV[0][t][r]) << 16);
            pk.y = (unsigned)f2bf_bits(accV[1][t][r]) | ((unsigned)f2bf_bits(accV[2][t][r]) << 16);
            *(uint2*)(hbuf + (size_t)(base + 4 * q + r) * 256 + (16 * t + m) * 4) = pk;
        }
    }
}

// ---------------- Kernel M: MFMA edge MLP (TPW tiles/wave; geometry pre-hoisted; W1,W2 in regs) ----------------
// W3T is XOR-swizzled (16B groups) -> conflict-free ds_read_b128.
// LDS: W3T 36864 + hbl 18432 = 55.3 KB (2 blocks/CU).
__global__ __launch_bounds__(512) void mlp_kernel(
    const unsigned short* __restrict__ rbq,        // [E][8] bf16 radial basis
    const void* __restrict__ W1,                   // [8,64] raw
    const unsigned short* __restrict__ W2q,        // [64*72] bf16 image (linear)
    const unsigned short* __restrict__ W3q,        // [256*72] bf16 image (swizzled)
    unsigned short* __restrict__ mixp,             // [SEG_E][64][4] bf16 packed
    int p_lo,
    const int* __restrict__ flag)
{
    bool f32 = (*flag == 0);
    __shared__ __align__(16) unsigned short W3T[256 * 72];
    __shared__ unsigned short hbl[8 * 64 * 18];
    int tid = threadIdx.x;
    for (int i = tid; i < 2304; i += 512) ((uint4*)W3T)[i] = ((const uint4*)W3q)[i];
    __syncthreads();
    int wave = tid >> 6, lane = tid & 63;
    int m = lane & 15, q = lane >> 4;
    unsigned short* hb = hbl + wave * (64 * 18);
    f32x4 zero4 = {0.f, 0.f, 0.f, 0.f};

    // tile-invariant A-fragments in registers (W1 raw; W2 from pre-built image)
    bf16x8 a1f[4];
    #pragma unroll
    for (int t = 0; t < 4; t++) {
        #pragma unroll
        for (int j = 0; j < 8; j++) a1f[t][j] = 0;
        if (q == 0) {
            #pragma unroll
            for (int j = 0; j < 8; j++)
                a1f[t][j] = (short)f2bf_bits(LDf(W1, j * 64 + 16 * t + m, f32));
        }
    }
    bf16x8 w2f[4][2];
    #pragma unroll
    for (int t = 0; t < 4; t++) {
        w2f[t][0] = *(const bf16x8*)(W2q + (16 * t + m) * 72 + 8 * q);
        w2f[t][1] = *(const bf16x8*)(W2q + (16 * t + m) * 72 + 32 + 8 * q);
    }

    int g0 = (q ^ (m & 7)) << 3;            // swizzled group for col-block q
    int g1 = ((4 + q) ^ (m & 7)) << 3;      // swizzled group for col-block 4+q

    int tile0 = (blockIdx.x * 8 + wave) * TPW;
    #pragma unroll 1
    for (int tt = 0; tt < TPW; tt++) {
        int tile = tile0 + tt;
        if (tile >= SEG_TILES) break;
        int p = p_lo + tile * 16 + m;

        bf16x8 b_rb;
        #pragma unroll
        for (int j = 0; j < 8; j++) b_rb[j] = 0;
        if (q == 0) b_rb = *(const bf16x8*)(rbq + (size_t)p * 8);

        #pragma unroll
        for (int t = 0; t < 4; t++) {
            f32x4 c = __builtin_amdgcn_mfma_f32_16x16x32_bf16(a1f[t], b_rb, zero4, 0, 0, 0);
            #pragma unroll
            for (int r = 0; r < 4; r++)
                hb[(16 * t + 4 * q + r) * 18 + m] = f2bf_bits(swishf(c[r] * INV8));
        }
        bf16x8 b2[2];
        #pragma unroll
        for (int h = 0; h < 2; h++)
            #pragma unroll
            for (int j = 0; j < 8; j++)
                b2[h][j] = (short)hb[(32 * h + 8 * q + j) * 18 + m];
        #pragma unroll
        for (int t = 0; t < 4; t++) {
            f32x4 c = __builtin_amdgcn_mfma_f32_16x16x32_bf16(w2f[t][0], b2[0], zero4, 0, 0, 0);
            c = __builtin_amdgcn_mfma_f32_16x16x32_bf16(w2f[t][1], b2[1], c, 0, 0, 0);
            #pragma unroll
            for (int r = 0; r < 4; r++)
                hb[(16 * t + 4 * q + r) * 18 + m] = f2bf_bits(swishf(c[r] * INV64));
        }
        bf16x8 b3[2];
        #pragma unroll
        for (int h = 0; h < 2; h++)
            #pragma unroll
            for (int j = 0; j < 8; j++)
                b3[h][j] = (short)hb[(32 * h + 8 * q + j) * 18 + m];
        // stage 3 packed: t3 = t3p + 4g; block g = mix_g; channel ch = 16*t3p + 4q + r
        size_t ebase = ((size_t)(tile * 16 + m)) * 256;   // shorts (512B per edge)
        #pragma unroll
        for (int t3p = 0; t3p < 4; t3p++) {
            f32x4 cg[4];
            #pragma unroll
            for (int g = 0; g < 4; g++) {
                int t3 = t3p + 4 * g;
                bf16x8 a0 = *(const bf16x8*)(W3T + (16 * t3 + m) * 72 + g0);
                bf16x8 a1 = *(const bf16x8*)(W3T + (16 * t3 + m) * 72 + g1);
                f32x4 c = __builtin_amdgcn_mfma_f32_16x16x32_bf16(a0, b3[0], zero4, 0, 0, 0);
                cg[g] = __builtin_amdgcn_mfma_f32_16x16x32_bf16(a1, b3[1], c, 0, 0, 0);
            }
            #pragma unroll
            for (int r = 0; r < 4; r += 2) {
                uint4 w;
                w.x = f2bf_bits(cg[0][r] * INV64)     | ((unsigned)f2bf_bits(cg[1][r] * INV64) << 16);
                w.y = f2bf_bits(cg[2][r] * INV64)     | ((unsigned)f2bf_bits(cg[3][r] * INV64) << 16);
                w.z = f2bf_bits(cg[0][r + 1] * INV64) | ((unsigned)f2bf_bits(cg[1][r + 1] * INV64) << 16);
                w.w = f2bf_bits(cg[2][r + 1] * INV64) | ((unsigned)f2bf_bits(cg[3][r + 1] * INV64) << 16);
                *(uint4*)(mixp + ebase + (size_t)(16 * t3p + 4 * q + r) * 4) = w;
            }
        }
    }
}

// ---------------- Kernel B: per-node aggregation (packed mix: 3 loads/edge) ----------------
__global__ __launch_bounds__(256) void agg_kernel(
    const unsigned short* __restrict__ hbuf,      // [N,64,4]
    const int* __restrict__ sorted_snd,
    const unsigned short* __restrict__ mixp,      // [SEG_E,64,4] packed
    const unsigned short* __restrict__ yq,        // [E,4]
    const int* __restrict__ offs,
    unsigned short* __restrict__ agg_s_b,         // [N,128] bf16
    unsigned short* __restrict__ agg_v_b,         // [N,384] bf16
    int slo, int shi)
{
    int tid = threadIdx.x, wave = tid >> 6, lane = tid & 63;
    int n = blockIdx.x * 4 + wave;
    if (n >= N_NODES) return;
    int beg = __builtin_amdgcn_readfirstlane(offs[n]);
    int end = __builtin_amdgcn_readfirstlane(offs[n + 1]);
    int lo = beg > slo ? beg : slo;
    int hi = end < shi ? end : shi;
    bool owner = (beg >= slo && beg < shi) || (beg >= shi && shi == N_EDGES);
    if (!owner && hi <= lo) return;
    unsigned short* aS = agg_s_b + (size_t)n * 128;
    unsigned short* aV = agg_v_b + (size_t)n * 384;
    float s0, s1, v0, v1, v2, v3, v4, v5;
    if (owner) {
        s0 = s1 = v0 = v1 = v2 = v3 = v4 = v5 = 0.f;
    } else {
        s0 = bfu(aS[lane]); s1 = bfu(aS[64 + lane]);
        v0 = bfu(aV[lane]); v1 = bfu(aV[64 + lane]); v2 = bfu(aV[128 + lane]);
        v3 = bfu(aV[192 + lane]); v4 = bfu(aV[256 + lane]); v5 = bfu(aV[320 + lane]);
    }
    for (int chunk = lo; chunk < hi; chunk += 64) {
        int cc = hi - chunk; if (cc > 64) cc = 64;
        // one vectorized load grabs up to 64 senders for this wave
        int sv = (lane < cc) ? sorted_snd[chunk + lane] : 0;
        int i = 0;
        for (; i + 3 < cc; i += 4) {
            uint2 h[4], mxw[4], yw[4];
            #pragma unroll
            for (int u = 0; u < 4; u++) {
                int snd = __builtin_amdgcn_readlane(sv, i + u);
                int p = chunk + i + u;
                h[u]   = *(const uint2*)(hbuf + (size_t)snd * 256 + lane * 4);
                mxw[u] = *(const uint2*)(mixp + (size_t)(p - slo) * 256 + lane * 4);
                yw[u]  = *(const uint2*)(yq + (size_t)p * 4);
            }
            #pragma unroll
            for (int u = 0; u < 4; u++) {
                float m_s = bflo(h[u].x), mv0 = bfhi(h[u].x), mv1 = bflo(h[u].y), mv2 = bfhi(h[u].y);
                float mix0 = bflo(mxw[u].x), mix1 = bfhi(mxw[u].x);
                float mix2 = bflo(mxw[u].y), mix3 = bfhi(mxw[u].y);
                float Yx = bflo(yw[u].x), Yy = bfhi(yw[u].x), Yz = bflo(yw[u].y);
                float tp0 = (mv0 * Yx + mv1 * Yy + mv2 * Yz) * INV_SQRT3;
                s0 = fmaf(m_s, mix0, s0);
                s1 = fmaf(tp0, mix1, s1);
                float t1 = m_s * mix3;
                v0 = fmaf(mv0, mix2, v0); v1 = fmaf(t1, Yx, v1);
                v2 = fmaf(mv1, mix2, v2); v3 = fmaf(t1, Yy, v3);
                v4 = fmaf(mv2, mix2, v4); v5 = fmaf(t1, Yz, v5);
            }
        }
        for (; i < cc; i++) {
            int snd = __builtin_amdgcn_readlane(sv, i);
            int p = chunk + i;
            uint2 hbv = *(const uint2*)(hbuf + (size_t)snd * 256 + lane * 4);
            uint2 mxw = *(const uint2*)(mixp + (size_t)(p - slo) * 256 + lane * 4);
            uint2 yw  = *(const uint2*)(yq + (size_t)p * 4);
            float m_s = bflo(hbv.x), mv0 = bfhi(hbv.x), mv1 = bflo(hbv.y), mv2 = bfhi(hbv.y);
            float mix0 = bflo(mxw.x), mix1 = bfhi(mxw.x);
            float mix2 = bflo(mxw.y), mix3 = bfhi(mxw.y);
            float Yx = bflo(yw.x), Yy = bfhi(yw.x), Yz = bflo(yw.y);
            float tp0 = (mv0 * Yx + mv1 * Yy + mv2 * Yz) * INV_SQRT3;
            s0 = fmaf(m_s, mix0, s0);
            s1 = fmaf(tp0, mix1, s1);
            float t1 = m_s * mix3;
            v0 = fmaf(mv0, mix2, v0); v1 = fmaf(t1, Yx, v1);
            v2 = fmaf(mv1, mix2, v2); v3 = fmaf(t1, Yy, v3);
            v4 = fmaf(mv2, mix2, v4); v5 = fmaf(t1, Yz, v5);
        }
    }
    aS[lane] = f2bf_bits(s0); aS[64 + lane] = f2bf_bits(s1);
    aV[lane] = f2bf_bits(v0); aV[64 + lane] = f2bf_bits(v1); aV[128 + lane] = f2bf_bits(v2);
    aV[192 + lane] = f2bf_bits(v3); aV[256 + lane] = f2bf_bits(v4); aV[320 + lane] = f2bf_bits(v5);
}

// ---------------- Kernel C: MFMA down-projection + skip + gate (swizzled As/Av) ----------------
__global__ __launch_bounds__(256) void node_final_kernel(
    const unsigned short* __restrict__ Wq_s,      // [5][128*200] bf16 image (swizzled)
    const unsigned short* __restrict__ Wq_v,      // [5][64*200] bf16 image (swizzled)
    const unsigned short* __restrict__ ns_b,      // [N,64]
    const unsigned short* __restrict__ nv_t,      // [3,N,64]
    const unsigned short* __restrict__ agg_s_b,   // [N,128]
    const unsigned short* __restrict__ agg_v_b,   // [N,384]
    const int* __restrict__ sorted_node,
    const int* __restrict__ sp_offs,         // [6]
    const int* __restrict__ tile_info,       // [16]
    void* __restrict__ out,
    const int* __restrict__ flag)
{
    bool f32 = (*flag == 0);
    int b = blockIdx.x;
    if (b >= tile_info[5]) return;
    __shared__ __align__(16) unsigned short As[128 * 200];
    __shared__ __align__(16) unsigned short Av[64 * 200];
    int sp = 0;
    #pragma unroll
    for (int s = 1; s < 5; s++) if (b >= tile_info[s]) sp = s;
    int tid = threadIdx.x;
    const uint4* ps = (const uint4*)(Wq_s + (size_t)sp * 25600);   // 3200 uint4 (verbatim)
    for (int i = tid; i < 3200; i += 256) ((uint4*)As)[i] = ps[i];
    const uint4* pv = (const uint4*)(Wq_v + (size_t)sp * 12800);   // 1600 uint4
    for (int i = tid; i < 1600; i += 256) ((uint4*)Av)[i] = pv[i];
    __syncthreads();
    int wave = tid >> 6, lane = tid & 63;
    int m = lane & 15, q = lane >> 4;
    int T = tile_info[8 + sp];
    int tl = (b - tile_info[sp]) * 4 + wave;
    if (tl >= T) return;
    int row = sp_offs[sp] + tl * 16;
    int cnt = sp_offs[sp + 1] - row; if (cnt > 16) cnt = 16;
    int mm = (m < cnt) ? m : 0;
    int node = sorted_node[row + mm];

    bf16x8 bs[6];
    {
        const unsigned short* a = agg_s_b + (size_t)node * 128;
        #pragma unroll
        for (int f = 0; f < 4; f++) bs[f] = *(const bf16x8*)(a + f * 32 + q * 8);
        const unsigned short* s = ns_b + (size_t)node * 64;
        #pragma unroll
        for (int f = 0; f < 2; f++) bs[4 + f] = *(const bf16x8*)(s + f * 32 + q * 8);
    }
    bf16x8 bv[3][6];
    #pragma unroll
    for (int c = 0; c < 3; c++) {
        const unsigned short* a = agg_v_b + (size_t)node * 384 + c * 128;
        #pragma unroll
        for (int f = 0; f < 4; f++) bv[c][f] = *(const bf16x8*)(a + f * 32 + q * 8);
        const unsigned short* s = nv_t + (size_t)c * N_NODES * 64 + (size_t)node * 64;
        #pragma unroll
        for (int f = 0; f < 2; f++) bv[c][4 + f] = *(const bf16x8*)(s + f * 32 + q * 8);
    }
    f32x4 z4 = {0.f, 0.f, 0.f, 0.f};
    int m7 = m & 7;
    float gate[4][4];
    #pragma unroll
    for (int t = 0; t < 4; t++) {
        f32x4 c = z4;
        #pragma unroll
        for (int f = 0; f < 6; f++) {
            bf16x8 a = *(const bf16x8*)(As + (16 * (4 + t) + m) * 200 + (((4 * f + q) ^ m7) << 3));
            c = __builtin_amdgcn_mfma_f32_16x16x32_bf16(a, bs[f], c, 0, 0, 0);
        }
        #pragma unroll
        for (int r = 0; r < 4; r++) gate[t][r] = swishf(c[r]);
    }
    #pragma unroll
    for (int t = 0; t < 4; t++) {
        f32x4 c = z4;
        #pragma unroll
        for (int f = 0; f < 6; f++) {
            bf16x8 a = *(const bf16x8*)(As + (16 * t + m) * 200 + (((4 * f + q) ^ m7) << 3));
            c = __builtin_amdgcn_mfma_f32_16x16x32_bf16(a, bs[f], c, 0, 0, 0);
        }
        if (m < cnt) {
            size_t base = (size_t)node * 256 + 16 * t + 4 * q;
            if (f32) {
                float4 o4 = { swishf(c[0]), swishf(c[1]), swishf(c[2]), swishf(c[3]) };
                *(float4*)((float*)out + base) = o4;
            } else {
                uint2 o2;
                o2.x = f2bf_bits(swishf(c[0])) | ((unsigned)f2bf_bits(swishf(c[1])) << 16);
                o2.y = f2bf_bits(swishf(c[2])) | ((unsigned)f2bf_bits(swishf(c[3])) << 16);
                *(uint2*)((unsigned short*)out + base) = o2;
            }
        }
    }
    #pragma unroll
    for (int t = 0; t < 4; t++) {
        f32x4 c0 = z4, c1 = z4, c2 = z4;
        #pragma unroll
        for (int f = 0; f < 6; f++) {
            bf16x8 a = *(const bf16x8*)(Av + (16 * t + m) * 200 + (((4 * f + q) ^ m7) << 3));
            c0 = __builtin_amdgcn_mfma_f32_16x16x32_bf16(a, bv[0][f], c0, 0, 0, 0);
            c1 = __builtin_amdgcn_mfma_f32_16x16x32_bf16(a, bv[1][f], c1, 0, 0, 0);
            c2 = __builtin_amdgcn_mfma_f32_16x16x32_bf16(a, bv[2][f], c2, 0, 0, 0);
        }
        if (m < cnt) {
            #pragma unroll
            for (int r = 0; r < 4; r++) {
                float g = gate[t][r];
                int o = 16 * t + 4 * q + r;
                size_t base = (size_t)node * 256 + 64 + (size_t)o * 3;
                if (f32) {
                    ((float*)out)[base + 0] = c0[r] * g;
                    ((float*)out)[base + 1] = c1[r] * g;
                    ((float*)out)[base + 2] = c2[r] * g;
                } else {
                    ((__hip_bfloat16*)out)[base + 0] = __float2bfloat16(c0[r] * g);
                    ((__hip_bfloat16*)out)[base + 1] = __float2bfloat16(c1[r] * g);
                    ((__hip_bfloat16*)out)[base + 2] = __float2bfloat16(c2[r] * g);
                }
            }
        }
    }
}

extern "C" void kernel_launch(void* const* d_in, const int* in_sizes, int n_in,
                              void* d_out, int out_size, void* d_ws, size_t ws_size,
                              hipStream_t stream) {
    const void* vectors      = d_in[0];
    const void* node_scalars = d_in[1];
    const void* node_vectors = d_in[2];
    const int* node_specie   = (const int*)d_in[3];
    const int* senders       = (const int*)d_in[4];
    const int* receivers     = (const int*)d_in[5];
    const void* W_up_s       = d_in[6];
    const void* W_up_v       = d_in[7];
    const void* W_skip_s     = d_in[8];
    const void* W_skip_v     = d_in[9];
    const void* W_mlp1       = d_in[10];
    const void* W_mlp2       = d_in[11];
    const void* W_mlp3       = d_in[12];
    const void* W_down_s     = d_in[13];
    const void* W_down_v     = d_in[14];

    char* ws = (char*)d_ws;
    size_t off = 0;
    auto alloc = [&](size_t bytes) { void* p = ws + off; off += (bytes + 255) & ~(size_t)255; return p; };
    unsigned short* hbuf     = (unsigned short*)alloc((size_t)N_NODES * 256 * 2);
    unsigned short* ns_b     = (unsigned short*)alloc((size_t)N_NODES * 64 * 2);
    unsigned short* nv_t     = (unsigned short*)alloc((size_t)N_NODES * 192 * 2);
    unsigned short* agg_s_b  = (unsigned short*)alloc((size_t)N_NODES * 128 * 2);
    unsigned short* agg_v_b  = (unsigned short*)alloc((size_t)N_NODES * 384 * 2);
    unsigned short* mixp     = (unsigned short*)alloc((size_t)SEG_E * 256 * 2);   // 122.88 MB packed
    unsigned short* yq       = (unsigned short*)alloc((size_t)N_EDGES * 4 * 2);
    unsigned short* rbq      = (unsigned short*)alloc((size_t)N_EDGES * 8 * 2);   // 7.68 MB
    unsigned short* Wup_sq   = (unsigned short*)alloc((size_t)64 * 72 * 2);
    unsigned short* Wup_vq   = (unsigned short*)alloc((size_t)64 * 72 * 2);
    unsigned short* Wq_s     = (unsigned short*)alloc((size_t)5 * 128 * 200 * 2);
    unsigned short* Wq_v     = (unsigned short*)alloc((size_t)5 * 64 * 200 * 2);
    unsigned short* W2q      = (unsigned short*)alloc((size_t)64 * 72 * 2);
    unsigned short* W3q      = (unsigned short*)alloc((size_t)256 * 72 * 2);
    int* cnt        = (int*)alloc((size_t)(N_NODES + 8) * 4);
    int* cnt5       = cnt + N_NODES;
    int* offs       = (int*)alloc((size_t)(N_NODES + 1) * 4);
    int* cursor     = (int*)alloc((size_t)N_NODES * 4);
    int* sorted_snd = (int*)alloc((size_t)N_EDGES * 4);
    int* sorted_node= (int*)alloc((size_t)N_NODES * 4);
    int* sp_offs    = (int*)alloc(16 * 4);
    int* cursor5    = (int*)alloc(16 * 4);
    int* tile_info  = (int*)alloc(16 * 4);
    int* partials   = (int*)alloc((size_t)(SCAN_BLOCKS + 1) * 4);
    int* pscan      = (int*)alloc((size_t)(SCAN_BLOCKS + 1) * 4);
    int* flag       = (int*)alloc(4);

    detect_kernel<<<dim3(1), dim3(64), 0, stream>>>((const unsigned short*)W_up_s, flag);
    (void)hipMemsetAsync(cnt, 0, (size_t)(N_NODES + 8) * 4, stream);

    wprep_kernel<<<dim3(64), dim3(256), 0, stream>>>(
        W_up_s, W_up_v, W_skip_s, W_skip_v, W_down_s, W_down_v, W_mlp2, W_mlp3,
        Wup_sq, Wup_vq, Wq_s, Wq_v, W2q, W3q, flag);

    hist_kernel<<<dim3(1875), dim3(256), 0, stream>>>(receivers, cnt);
    partial_kernel<<<dim3(SCAN_BLOCKS), dim3(256), 0, stream>>>(cnt, partials);
    scanp_kernel<<<dim3(1), dim3(256), 0, stream>>>(partials, pscan);
    offs_kernel<<<dim3(SCAN_BLOCKS), dim3(256), 0, stream>>>(cnt, pscan, offs, cursor);
    scatter_kernel<<<dim3(1875), dim3(256), 0, stream>>>(receivers, senders, vectors,
                                                         cursor, sorted_snd, yq, rbq, flag);

    hist5_kernel<<<dim3(157), dim3(256), 0, stream>>>(node_specie, cnt5);
    scan5_kernel<<<dim3(1), dim3(64), 0, stream>>>(cnt5, sp_offs, cursor5, tile_info);
    scatter5_kernel<<<dim3(157), dim3(256), 0, stream>>>(node_specie, cursor5, sorted_node);

    // 625 blocks * 4 waves * 16 nodes = 40000
    node_up_kernel<<<dim3(625), dim3(256), 0, stream>>>(
        node_scalars, node_vectors, Wup_sq, Wup_vq, hbuf, ns_b, nv_t, flag);

    const int MLP_BLOCKS = (SEG_TILES + 8 * TPW - 1) / (8 * TPW);   // 469
    for (int s = 0; s < SEG; s++) {
        int p_lo = s * SEG_E;
        mlp_kernel<<<dim3(MLP_BLOCKS), dim3(512), 0, stream>>>(
            rbq, W_mlp1, W2q, W3q, mixp, p_lo, flag);
        agg_kernel<<<dim3(10000), dim3(256), 0, stream>>>(
            hbuf, sorted_snd, mixp, yq, offs, agg_s_b, agg_v_b, p_lo, p_lo + SEG_E);
    }

    node_final_kernel<<<dim3(640), dim3(256), 0, stream>>>(
        Wq_s, Wq_v, ns_b, nv_t, agg_s_b, agg_v_b,
        sorted_node, sp_offs, tile_info, d_out, flag);
}

// Round 13
// 485.993 us; speedup vs baseline: 1.0124x; 1.0124x over previous
//
#include <hip/hip_runtime.h>
#include <hip/hip_bf16.h>

#define N_NODES 40000
#define N_EDGES 480000
#define SEG 2
#define SEG_E (N_EDGES / SEG)      // 240000
#define SEG_TILES (SEG_E / 16)     // 15000
#define SCAN_BLOCKS 157            // ceil(40000/256)
#define TPW 4                      // tiles per wave in mlp_kernel (best measured)

typedef short bf16x8 __attribute__((ext_vector_type(8)));
typedef float f32x4 __attribute__((ext_vector_type(4)));

__device__ __forceinline__ float bf2f(__hip_bfloat16 x) { return __bfloat162float(x); }

__device__ __forceinline__ float swishf(float x) { return x / (1.0f + __expf(-x)); }

__device__ __forceinline__ float bflo(unsigned u) { union { unsigned u; float f; } w; w.u = u << 16; return w.f; }
__device__ __forceinline__ float bfhi(unsigned u) { union { unsigned u; float f; } w; w.u = u & 0xffff0000u; return w.f; }
__device__ __forceinline__ float bfu(unsigned short u) { union { unsigned u; float f; } w; w.u = ((unsigned)u) << 16; return w.f; }

__device__ __forceinline__ unsigned short f2bf_bits(float x) {
    union { __hip_bfloat16 h; unsigned short u; } c; c.h = __float2bfloat16(x); return c.u;
}

__constant__ const float INV8 = 0.35355339059327373f;
__constant__ const float INV64 = 0.125f;
__constant__ const float INV128 = 0.08838834764831845f;
__constant__ const float INV_NN = 0.2886751345948129f;   // 1/sqrt(12)
__constant__ const float SQRT2 = 1.4142135623730951f;
__constant__ const float SQRT3 = 1.7320508075688772f;
__constant__ const float INV_SQRT3 = 0.5773502691896258f;
__constant__ const float PI_F = 3.14159265358979323846f;

// runtime-dtype load: flag==0 => f32 inputs; flag!=0 => bf16 inputs.
__device__ __forceinline__ float LDf(const void* p, size_t i, bool f32) {
    float v;
    if (f32) v = ((const float*)p)[i];
    else     v = bf2f(((const __hip_bfloat16*)p)[i]);
    return v;
}
// load 8 consecutive elements as float (16B-aligned in both dtype paths)
__device__ __forceinline__ void load_f8r(const void* p, size_t i, bool f32, float* out) {
    if (f32) {
        const float4* q4 = (const float4*)((const float*)p + i);
        float4 a = q4[0], b = q4[1];
        out[0] = a.x; out[1] = a.y; out[2] = a.z; out[3] = a.w;
        out[4] = b.x; out[5] = b.y; out[6] = b.z; out[7] = b.w;
    } else {
        bf16x8 v = *(const bf16x8*)((const unsigned short*)p + i);
        #pragma unroll
        for (int j = 0; j < 8; j++) out[j] = bfu((unsigned short)v[j]);
    }
}

// ---------------- dtype probe ----------------
// flag = 1 iff weight buffer looks like bf16 (every 16-bit word has a sane exponent field)
__global__ void detect_kernel(const unsigned short* __restrict__ w, int* __restrict__ flag) {
    int lane = threadIdx.x;
    int cnt = 0;
    for (int i = lane; i < 2048; i += 64) {
        unsigned e = (w[2 * i] >> 7) & 0xFF;
        if (e >= 110 && e <= 133) cnt++;
    }
    #pragma unroll
    for (int off = 32; off > 0; off >>= 1) cnt += __shfl_down(cnt, off, 64);
    if (lane == 0) *flag = (cnt > 1024) ? 1 : 0;
}

// ---------------- weight pre-conversion (once): f32/bf16 -> bf16 LDS-image layouts ----------------
__global__ __launch_bounds__(256) void wprep_kernel(
    const void* __restrict__ W_up_s, const void* __restrict__ W_up_v,
    const void* __restrict__ W_skip_s, const void* __restrict__ W_skip_v,
    const void* __restrict__ W_down_s, const void* __restrict__ W_down_v,
    const void* __restrict__ W_mlp2, const void* __restrict__ W_mlp3,
    unsigned short* __restrict__ Wup_sq, unsigned short* __restrict__ Wup_vq,
    unsigned short* __restrict__ Wq_s, unsigned short* __restrict__ Wq_v,
    unsigned short* __restrict__ W2q, unsigned short* __restrict__ W3q,
    const int* __restrict__ flag)
{
    bool f32 = (*flag == 0);
    const float SC = INV128 * INV_NN;
    int gid = blockIdx.x * 256 + threadIdx.x;
    int gs = gridDim.x * 256;
    // node_up weights: [o][k], stride 72, *INV64
    for (int i = gid; i < 4096; i += gs) {
        int o = i & 63, k = i >> 6;
        Wup_sq[o * 72 + k] = f2bf_bits(LDf(W_up_s, k * 64 + o, f32) * INV64);
        Wup_vq[o * 72 + k] = f2bf_bits(LDf(W_up_v, k * 64 + o, f32) * INV64);
    }
    // node_final As: per-species [128][200], k<192
    for (int i = gid; i < 5 * 128 * 192; i += gs) {
        int sp = i / 24576, r = i - sp * 24576;
        int o = r / 192, k = r - o * 192;
        float w = (k < 128) ? LDf(W_down_s, k * 128 + o, f32) * SC
                            : LDf(W_skip_s, sp * 8192 + (k - 128) * 128 + o, f32) * INV64;
        Wq_s[sp * 25600 + o * 200 + k] = f2bf_bits(w);
    }
    // node_final Av: per-species [64][200], k<192
    for (int i = gid; i < 5 * 64 * 192; i += gs) {
        int sp = i / 12288, r = i - sp * 12288;
        int o = r / 192, k = r - o * 192;
        float w = (k < 128) ? LDf(W_down_v, k * 64 + o, f32) * SC
                            : LDf(W_skip_v, sp * 4096 + (k - 128) * 64 + o, f32) * INV64;
        Wq_v[sp * 12800 + o * 200 + k] = f2bf_bits(w);
    }
    // mlp W3T: [256][72]
    for (int i = gid; i < 16384; i += gs) {
        int o = i & 255, k = i >> 8;
        W3q[o * 72 + k] = f2bf_bits(LDf(W_mlp3, k * 256 + o, f32));
    }
    // mlp W2T: [64][72]
    for (int i = gid; i < 4096; i += gs) {
        int o = i & 63, k = i >> 6;
        W2q[o * 72 + k] = f2bf_bits(LDf(W_mlp2, k * 64 + o, f32));
    }
}

// ---------------- counting sort of edges by receiver ----------------
__global__ __launch_bounds__(256) void hist_kernel(const int* __restrict__ receivers,
                                                   int* __restrict__ cnt) {
    int e = blockIdx.x * 256 + threadIdx.x;
    if (e < N_EDGES) atomicAdd(&cnt[receivers[e]], 1);
}

__global__ __launch_bounds__(256) void partial_kernel(const int* __restrict__ cnt,
                                                      int* __restrict__ partials) {
    __shared__ int red[4];
    int idx = blockIdx.x * 256 + threadIdx.x;
    int v = (idx < N_NODES) ? cnt[idx] : 0;
    #pragma unroll
    for (int off = 32; off > 0; off >>= 1) v += __shfl_down(v, off, 64);
    int wave = threadIdx.x >> 6, lane = threadIdx.x & 63;
    if (lane == 0) red[wave] = v;
    __syncthreads();
    if (threadIdx.x == 0) partials[blockIdx.x] = red[0] + red[1] + red[2] + red[3];
}

__global__ __launch_bounds__(256) void scanp_kernel(const int* __restrict__ partials,
                                                    int* __restrict__ pscan) {
    __shared__ int buf[256];
    int t = threadIdx.x;
    int v = (t < SCAN_BLOCKS) ? partials[t] : 0;
    buf[t] = v;
    __syncthreads();
    for (int off = 1; off < 256; off <<= 1) {
        int tmp = (t >= off) ? buf[t - off] : 0;
        __syncthreads();
        buf[t] += tmp;
        __syncthreads();
    }
    if (t < SCAN_BLOCKS) pscan[t] = buf[t] - v;   // exclusive
}

__global__ __launch_bounds__(256) void offs_kernel(const int* __restrict__ cnt,
                                                   const int* __restrict__ pscan,
                                                   int* __restrict__ offs,
                                                   int* __restrict__ cursor) {
    __shared__ int buf[256];
    int b = blockIdx.x, t = threadIdx.x;
    int idx = b * 256 + t;
    int v = (idx < N_NODES) ? cnt[idx] : 0;
    buf[t] = v;
    __syncthreads();
    for (int off = 1; off < 256; off <<= 1) {
        int tmp = (t >= off) ? buf[t - off] : 0;
        __syncthreads();
        buf[t] += tmp;
        __syncthreads();
    }
    int exc = buf[t] - v + pscan[b];
    if (idx < N_NODES) { offs[idx] = exc; cursor[idx] = exc; }
    if (idx == N_NODES - 1) offs[N_NODES] = exc + v;
}

// scatter: sort senders by receiver AND pre-compute ALL per-edge geometry:
// Y (sph harmonics, bf16 yq) and radial basis rb[8] (bf16x8 rbq), in sorted order.
__global__ __launch_bounds__(256) void scatter_kernel(const int* __restrict__ receivers,
                                                      const int* __restrict__ senders,
                                                      const void* __restrict__ vectors,
                                                      int* __restrict__ cursor,
                                                      int* __restrict__ sorted_snd,
                                                      unsigned short* __restrict__ yq,
                                                      unsigned short* __restrict__ rbq,
                                                      const int* __restrict__ flag) {
    bool f32 = (*flag == 0);
    int e = blockIdx.x * 256 + threadIdx.x;
    if (e < N_EDGES) {
        float vx = LDf(vectors, (size_t)e * 3 + 0, f32);
        float vy = LDf(vectors, (size_t)e * 3 + 1, f32);
        float vz = LDf(vectors, (size_t)e * 3 + 2, f32);
        float len2 = vx * vx + vy * vy + vz * vz;
        float len = sqrtf(len2);
        float Yx = 0.f, Yy = 0.f, Yz = 0.f;
        float rb[8];
        if (len > 0.f) {
            float inv = 1.f / len;
            Yx = SQRT3 * vx * inv; Yy = SQRT3 * vy * inv; Yz = SQRT3 * vz * inv;
            float x6 = len2 * len2 * len2;
            float env = (len < 1.f) ? fmaf(x6, fmaf(len, fmaf(len, -21.f, 48.f), -28.f), 1.f) : 0.f;
            float c = SQRT2 * inv * env;
            #pragma unroll
            for (int k = 0; k < 8; k++) rb[k] = c * __sinf((float)(k + 1) * PI_F * len);
        } else {
            #pragma unroll
            for (int k = 0; k < 8; k++) rb[k] = 0.f;
        }
        int p = atomicAdd(&cursor[receivers[e]], 1);
        sorted_snd[p] = senders[e];
        uint2 yw;
        yw.x = f2bf_bits(Yx) | ((unsigned)f2bf_bits(Yy) << 16);
        yw.y = f2bf_bits(Yz);
        *(uint2*)(yq + (size_t)p * 4) = yw;
        bf16x8 r8;
        #pragma unroll
        for (int k = 0; k < 8; k++) r8[k] = (short)f2bf_bits(rb[k]);
        *(bf16x8*)(rbq + (size_t)p * 8) = r8;
    }
}

// ---------------- counting sort of nodes by species ----------------
__global__ __launch_bounds__(256) void hist5_kernel(const int* __restrict__ specie,
                                                    int* __restrict__ cnt5) {
    int n = blockIdx.x * 256 + threadIdx.x;
    int lane = threadIdx.x & 63;
    int sp = (n < N_NODES) ? specie[n] : -1;
    #pragma unroll
    for (int s = 0; s < 5; s++) {
        unsigned long long mask = __ballot(sp == s);
        if (mask != 0ull) {
            int leader = __builtin_ctzll(mask);
            if (lane == leader) atomicAdd(&cnt5[s], __popcll(mask));
        }
    }
}

__global__ void scan5_kernel(const int* __restrict__ cnt5, int* __restrict__ sp_offs,
                             int* __restrict__ cursor5, int* __restrict__ tile_info) {
    if (threadIdx.x != 0 || blockIdx.x != 0) return;
    int run = 0, tb = 0;
    for (int s = 0; s < 5; s++) {
        sp_offs[s] = run; cursor5[s] = run;
        tile_info[s] = tb;
        int c = cnt5[s];
        int T = (c + 15) >> 4;
        tile_info[8 + s] = T;
        tb += (T + 3) >> 2;
        run += c;
    }
    sp_offs[5] = run;
    tile_info[5] = tb;
}

__global__ __launch_bounds__(256) void scatter5_kernel(const int* __restrict__ specie,
                                                       int* __restrict__ cursor5,
                                                       int* __restrict__ sorted_node) {
    int n = blockIdx.x * 256 + threadIdx.x;
    int lane = threadIdx.x & 63;
    int sp = (n < N_NODES) ? specie[n] : -1;
    #pragma unroll
    for (int s = 0; s < 5; s++) {
        unsigned long long mask = __ballot(sp == s);
        if (mask != 0ull) {
            int leader = __builtin_ctzll(mask);
            int base = 0;
            if (lane == leader) base = atomicAdd(&cursor5[s], __popcll(mask));
            base = __shfl(base, leader);
            if (sp == s) {
                int prefix = __popcll(mask & ((1ull << lane) - 1ull));
                sorted_node[base + prefix] = n;
            }
        }
    }
}

// ---------------- Kernel A: per-node up-projection via MFMA (+ bf16 input packing) ----------------
__global__ __launch_bounds__(256) void node_up_kernel(
    const void* __restrict__ node_scalars,
    const void* __restrict__ node_vectors,
    const unsigned short* __restrict__ Wup_sq,
    const unsigned short* __restrict__ Wup_vq,
    unsigned short* __restrict__ hbuf,
    unsigned short* __restrict__ ns_b,
    unsigned short* __restrict__ nv_t,
    const int* __restrict__ flag)
{
    bool f32 = (*flag == 0);
    __shared__ __align__(16) unsigned short WsT[64 * 72];   // [o][k], *INV64 folded
    __shared__ __align__(16) unsigned short WvT[64 * 72];
    int tid = threadIdx.x;
    for (int i = tid; i < 576; i += 256) {                  // 4608 shorts = 576 uint4 each
        ((uint4*)WsT)[i] = ((const uint4*)Wup_sq)[i];
        ((uint4*)WvT)[i] = ((const uint4*)Wup_vq)[i];
    }
    __syncthreads();
    int wave = tid >> 6, lane = tid & 63;
    int m = lane & 15, q = lane >> 4;
    int base = (blockIdx.x * 4 + wave) * 16;         // 16 nodes per wave; 625 blocks * 64 = 40000

    f32x4 accS[4];
    f32x4 accV[3][4];
    #pragma unroll
    for (int t = 0; t < 4; t++) {
        accS[t] = f32x4{0.f, 0.f, 0.f, 0.f};
        #pragma unroll
        for (int c = 0; c < 3; c++) accV[c][t] = f32x4{0.f, 0.f, 0.f, 0.f};
    }

    #pragma unroll
    for (int kk = 0; kk < 2; kk++) {
        int i0 = kk * 32 + 8 * q;                    // k-slice this lane owns
        float fs[8];
        load_f8r(node_scalars, (size_t)(base + m) * 64 + i0, f32, fs);
        bf16x8 aS;
        #pragma unroll
        for (int j = 0; j < 8; j++) aS[j] = (short)f2bf_bits(fs[j]);
        *(bf16x8*)(ns_b + (size_t)(base + m) * 64 + i0) = aS;
        float fv[24];
        size_t vbase = (size_t)(base + m) * 192 + (size_t)i0 * 3;
        load_f8r(node_vectors, vbase,      f32, fv);
        load_f8r(node_vectors, vbase + 8,  f32, fv + 8);
        load_f8r(node_vectors, vbase + 16, f32, fv + 16);
        bf16x8 aV[3];
        #pragma unroll
        for (int c = 0; c < 3; c++) {
            #pragma unroll
            for (int j = 0; j < 8; j++) aV[c][j] = (short)f2bf_bits(fv[3 * j + c]);
            *(bf16x8*)(nv_t + (size_t)c * N_NODES * 64 + (size_t)(base + m) * 64 + i0) = aV[c];
        }
        #pragma unroll
        for (int t = 0; t < 4; t++) {
            bf16x8 bS = *(const bf16x8*)(WsT + (16 * t + m) * 72 + kk * 32 + 8 * q);
            bf16x8 bV = *(const bf16x8*)(WvT + (16 * t + m) * 72 + kk * 32 + 8 * q);
            accS[t]    = __builtin_amdgcn_mfma_f32_16x16x32_bf16(aS,    bS, accS[t],    0, 0, 0);
            accV[0][t] = __builtin_amdgcn_mfma_f32_16x16x32_bf16(aV[0], bV, accV[0][t], 0, 0, 0);
            accV[1][t] = __builtin_amdgcn_mfma_f32_16x16x32_bf16(aV[1], bV, accV[1][t], 0, 0, 0);
            accV[2][t] = __builtin_amdgcn_mfma_f32_16x16x32_bf16(aV[2], bV, accV[2][t], 0, 0, 0);
        }
    }
    #pragma unroll
    for (int t = 0; t < 4; t++) {
        #pragma unroll
        for (int r = 0; r < 4; r++) {
            uint2 pk;
            pk.x = (unsigned)f2bf_bits(accS[t][r])    | ((unsigned)f2bf_bits(accV[0][t][r]) << 16);
            pk.y = (unsigned)f2bf_bits(accV[1][t][r]) | ((unsigned)f2bf_bits(accV[2][t][r]) << 16);
            *(uint2*)(hbuf + (size_t)(base + 4 * q + r) * 256 + (16 * t + m) * 4) = pk;
        }
    }
}

// ---------------- Kernel M: MFMA edge MLP (TPW tiles/wave; geometry pre-hoisted; W1,W2 in regs) ----------------
// Output mix PACKED per-channel: mixp[e][ch] = {mix0..mix3}(ch) as 4 bf16 (8B) -> agg reads 1 uint2/edge.
// LDS: W3T 36864 + hbl 18432 = 55.3 KB (2 blocks/CU).
__global__ __launch_bounds__(512) void mlp_kernel(
    const unsigned short* __restrict__ rbq,        // [E][8] bf16 radial basis
    const void* __restrict__ W1,                   // [8,64] raw
    const unsigned short* __restrict__ W2q,        // [64*72] bf16 image
    const unsigned short* __restrict__ W3q,        // [256*72] bf16 image
    unsigned short* __restrict__ mixp,             // [SEG_E][64][4] bf16 packed
    int p_lo,
    const int* __restrict__ flag)
{
    bool f32 = (*flag == 0);
    __shared__ __align__(16) unsigned short W3T[256 * 72];
    __shared__ unsigned short hbl[8 * 64 * 18];
    int tid = threadIdx.x;
    for (int i = tid; i < 2304; i += 512) ((uint4*)W3T)[i] = ((const uint4*)W3q)[i];
    __syncthreads();
    int wave = tid >> 6, lane = tid & 63;
    int m = lane & 15, q = lane >> 4;
    unsigned short* hb = hbl + wave * (64 * 18);
    f32x4 zero4 = {0.f, 0.f, 0.f, 0.f};

    // tile-invariant A-fragments in registers (W1 raw; W2 from pre-built image)
    bf16x8 a1f[4];
    #pragma unroll
    for (int t = 0; t < 4; t++) {
        #pragma unroll
        for (int j = 0; j < 8; j++) a1f[t][j] = 0;
        if (q == 0) {
            #pragma unroll
            for (int j = 0; j < 8; j++)
                a1f[t][j] = (short)f2bf_bits(LDf(W1, j * 64 + 16 * t + m, f32));
        }
    }
    bf16x8 w2f[4][2];
    #pragma unroll
    for (int t = 0; t < 4; t++) {
        w2f[t][0] = *(const bf16x8*)(W2q + (16 * t + m) * 72 + 8 * q);
        w2f[t][1] = *(const bf16x8*)(W2q + (16 * t + m) * 72 + 32 + 8 * q);
    }

    int tile0 = (blockIdx.x * 8 + wave) * TPW;
    #pragma unroll 1
    for (int tt = 0; tt < TPW; tt++) {
        int tile = tile0 + tt;
        if (tile >= SEG_TILES) break;
        int p = p_lo + tile * 16 + m;

        bf16x8 b_rb;
        #pragma unroll
        for (int j = 0; j < 8; j++) b_rb[j] = 0;
        if (q == 0) b_rb = *(const bf16x8*)(rbq + (size_t)p * 8);

        #pragma unroll
        for (int t = 0; t < 4; t++) {
            f32x4 c = __builtin_amdgcn_mfma_f32_16x16x32_bf16(a1f[t], b_rb, zero4, 0, 0, 0);
            #pragma unroll
            for (int r = 0; r < 4; r++)
                hb[(16 * t + 4 * q + r) * 18 + m] = f2bf_bits(swishf(c[r] * INV8));
        }
        bf16x8 b2[2];
        #pragma unroll
        for (int h = 0; h < 2; h++)
            #pragma unroll
            for (int j = 0; j < 8; j++)
                b2[h][j] = (short)hb[(32 * h + 8 * q + j) * 18 + m];
        #pragma unroll
        for (int t = 0; t < 4; t++) {
            f32x4 c = __builtin_amdgcn_mfma_f32_16x16x32_bf16(w2f[t][0], b2[0], zero4, 0, 0, 0);
            c = __builtin_amdgcn_mfma_f32_16x16x32_bf16(w2f[t][1], b2[1], c, 0, 0, 0);
            #pragma unroll
            for (int r = 0; r < 4; r++)
                hb[(16 * t + 4 * q + r) * 18 + m] = f2bf_bits(swishf(c[r] * INV64));
        }
        bf16x8 b3[2];
        #pragma unroll
        for (int h = 0; h < 2; h++)
            #pragma unroll
            for (int j = 0; j < 8; j++)
                b3[h][j] = (short)hb[(32 * h + 8 * q + j) * 18 + m];
        // stage 3 packed: t3 = t3p + 4g; block g = mix_g; channel ch = 16*t3p + 4q + r
        size_t ebase = ((size_t)(tile * 16 + m)) * 256;   // shorts (512B per edge)
        #pragma unroll
        for (int t3p = 0; t3p < 4; t3p++) {
            f32x4 cg[4];
            #pragma unroll
            for (int g = 0; g < 4; g++) {
                int t3 = t3p + 4 * g;
                bf16x8 a0 = *(const bf16x8*)(W3T + (16 * t3 + m) * 72 + 8 * q);
                bf16x8 a1 = *(const bf16x8*)(W3T + (16 * t3 + m) * 72 + 32 + 8 * q);
                f32x4 c = __builtin_amdgcn_mfma_f32_16x16x32_bf16(a0, b3[0], zero4, 0, 0, 0);
                cg[g] = __builtin_amdgcn_mfma_f32_16x16x32_bf16(a1, b3[1], c, 0, 0, 0);
            }
            #pragma unroll
            for (int r = 0; r < 4; r += 2) {
                uint4 w;
                w.x = f2bf_bits(cg[0][r] * INV64)     | ((unsigned)f2bf_bits(cg[1][r] * INV64) << 16);
                w.y = f2bf_bits(cg[2][r] * INV64)     | ((unsigned)f2bf_bits(cg[3][r] * INV64) << 16);
                w.z = f2bf_bits(cg[0][r + 1] * INV64) | ((unsigned)f2bf_bits(cg[1][r + 1] * INV64) << 16);
                w.w = f2bf_bits(cg[2][r + 1] * INV64) | ((unsigned)f2bf_bits(cg[3][r + 1] * INV64) << 16);
                *(uint4*)(mixp + ebase + (size_t)(16 * t3p + 4 * q + r) * 4) = w;
            }
        }
    }
}

// ---------------- Kernel B: per-node aggregation (packed mix: 3 loads/edge) ----------------
__global__ __launch_bounds__(256) void agg_kernel(
    const unsigned short* __restrict__ hbuf,      // [N,64,4]
    const int* __restrict__ sorted_snd,
    const unsigned short* __restrict__ mixp,      // [SEG_E,64,4] packed
    const unsigned short* __restrict__ yq,        // [E,4]
    const int* __restrict__ offs,
    unsigned short* __restrict__ agg_s_b,         // [N,128] bf16
    unsigned short* __restrict__ agg_v_b,         // [N,384] bf16
    int slo, int shi)
{
    int tid = threadIdx.x, wave = tid >> 6, lane = tid & 63;
    int n = blockIdx.x * 4 + wave;
    if (n >= N_NODES) return;
    int beg = __builtin_amdgcn_readfirstlane(offs[n]);
    int end = __builtin_amdgcn_readfirstlane(offs[n + 1]);
    int lo = beg > slo ? beg : slo;
    int hi = end < shi ? end : shi;
    bool owner = (beg >= slo && beg < shi) || (beg >= shi && shi == N_EDGES);
    if (!owner && hi <= lo) return;
    unsigned short* aS = agg_s_b + (size_t)n * 128;
    unsigned short* aV = agg_v_b + (size_t)n * 384;
    float s0, s1, v0, v1, v2, v3, v4, v5;
    if (owner) {
        s0 = s1 = v0 = v1 = v2 = v3 = v4 = v5 = 0.f;
    } else {
        s0 = bfu(aS[lane]); s1 = bfu(aS[64 + lane]);
        v0 = bfu(aV[lane]); v1 = bfu(aV[64 + lane]); v2 = bfu(aV[128 + lane]);
        v3 = bfu(aV[192 + lane]); v4 = bfu(aV[256 + lane]); v5 = bfu(aV[320 + lane]);
    }
    for (int chunk = lo; chunk < hi; chunk += 64) {
        int cc = hi - chunk; if (cc > 64) cc = 64;
        // one vectorized load grabs up to 64 senders for this wave
        int sv = (lane < cc) ? sorted_snd[chunk + lane] : 0;
        int i = 0;
        for (; i + 3 < cc; i += 4) {
            uint2 h[4], mxw[4], yw[4];
            #pragma unroll
            for (int u = 0; u < 4; u++) {
                int snd = __builtin_amdgcn_readlane(sv, i + u);
                int p = chunk + i + u;
                h[u]   = *(const uint2*)(hbuf + (size_t)snd * 256 + lane * 4);
                mxw[u] = *(const uint2*)(mixp + (size_t)(p - slo) * 256 + lane * 4);
                yw[u]  = *(const uint2*)(yq + (size_t)p * 4);
            }
            #pragma unroll
            for (int u = 0; u < 4; u++) {
                float m_s = bflo(h[u].x), mv0 = bfhi(h[u].x), mv1 = bflo(h[u].y), mv2 = bfhi(h[u].y);
                float mix0 = bflo(mxw[u].x), mix1 = bfhi(mxw[u].x);
                float mix2 = bflo(mxw[u].y), mix3 = bfhi(mxw[u].y);
                float Yx = bflo(yw[u].x), Yy = bfhi(yw[u].x), Yz = bflo(yw[u].y);
                float tp0 = (mv0 * Yx + mv1 * Yy + mv2 * Yz) * INV_SQRT3;
                s0 = fmaf(m_s, mix0, s0);
                s1 = fmaf(tp0, mix1, s1);
                float t1 = m_s * mix3;
                v0 = fmaf(mv0, mix2, v0); v1 = fmaf(t1, Yx, v1);
                v2 = fmaf(mv1, mix2, v2); v3 = fmaf(t1, Yy, v3);
                v4 = fmaf(mv2, mix2, v4); v5 = fmaf(t1, Yz, v5);
            }
        }
        for (; i < cc; i++) {
            int snd = __builtin_amdgcn_readlane(sv, i);
            int p = chunk + i;
            uint2 hbv = *(const uint2*)(hbuf + (size_t)snd * 256 + lane * 4);
            uint2 mxw = *(const uint2*)(mixp + (size_t)(p - slo) * 256 + lane * 4);
            uint2 yw  = *(const uint2*)(yq + (size_t)p * 4);
            float m_s = bflo(hbv.x), mv0 = bfhi(hbv.x), mv1 = bflo(hbv.y), mv2 = bfhi(hbv.y);
            float mix0 = bflo(mxw.x), mix1 = bfhi(mxw.x);
            float mix2 = bflo(mxw.y), mix3 = bfhi(mxw.y);
            float Yx = bflo(yw.x), Yy = bfhi(yw.x), Yz = bflo(yw.y);
            float tp0 = (mv0 * Yx + mv1 * Yy + mv2 * Yz) * INV_SQRT3;
            s0 = fmaf(m_s, mix0, s0);
            s1 = fmaf(tp0, mix1, s1);
            float t1 = m_s * mix3;
            v0 = fmaf(mv0, mix2, v0); v1 = fmaf(t1, Yx, v1);
            v2 = fmaf(mv1, mix2, v2); v3 = fmaf(t1, Yy, v3);
            v4 = fmaf(mv2, mix2, v4); v5 = fmaf(t1, Yz, v5);
        }
    }
    aS[lane] = f2bf_bits(s0); aS[64 + lane] = f2bf_bits(s1);
    aV[lane] = f2bf_bits(v0); aV[64 + lane] = f2bf_bits(v1); aV[128 + lane] = f2bf_bits(v2);
    aV[192 + lane] = f2bf_bits(v3); aV[256 + lane] = f2bf_bits(v4); aV[320 + lane] = f2bf_bits(v5);
}

// ---------------- Kernel C: MFMA down-projection + skip + gate ----------------
__global__ __launch_bounds__(256) void node_final_kernel(
    const unsigned short* __restrict__ Wq_s,      // [5][128*200] bf16 image
    const unsigned short* __restrict__ Wq_v,      // [5][64*200] bf16 image
    const unsigned short* __restrict__ ns_b,      // [N,64]
    const unsigned short* __restrict__ nv_t,      // [3,N,64]
    const unsigned short* __restrict__ agg_s_b,   // [N,128]
    const unsigned short* __restrict__ agg_v_b,   // [N,384]
    const int* __restrict__ sorted_node,
    const int* __restrict__ sp_offs,         // [6]
    const int* __restrict__ tile_info,       // [16]
    void* __restrict__ out,
    const int* __restrict__ flag)
{
    bool f32 = (*flag == 0);
    int b = blockIdx.x;
    if (b >= tile_info[5]) return;
    __shared__ __align__(16) unsigned short As[128 * 200];
    __shared__ __align__(16) unsigned short Av[64 * 200];
    int sp = 0;
    #pragma unroll
    for (int s = 1; s < 5; s++) if (b >= tile_info[s]) sp = s;
    int tid = threadIdx.x;
    const uint4* ps = (const uint4*)(Wq_s + (size_t)sp * 25600);   // 3200 uint4
    for (int i = tid; i < 3200; i += 256) ((uint4*)As)[i] = ps[i];
    const uint4* pv = (const uint4*)(Wq_v + (size_t)sp * 12800);   // 1600 uint4
    for (int i = tid; i < 1600; i += 256) ((uint4*)Av)[i] = pv[i];
    __syncthreads();
    int wave = tid >> 6, lane = tid & 63;
    int m = lane & 15, q = lane >> 4;
    int T = tile_info[8 + sp];
    int tl = (b - tile_info[sp]) * 4 + wave;
    if (tl >= T) return;
    int row = sp_offs[sp] + tl * 16;
    int cnt = sp_offs[sp + 1] - row; if (cnt > 16) cnt = 16;
    int mm = (m < cnt) ? m : 0;
    int node = sorted_node[row + mm];

    bf16x8 bs[6];
    {
        const unsigned short* a = agg_s_b + (size_t)node * 128;
        #pragma unroll
        for (int f = 0; f < 4; f++) bs[f] = *(const bf16x8*)(a + f * 32 + q * 8);
        const unsigned short* s = ns_b + (size_t)node * 64;
        #pragma unroll
        for (int f = 0; f < 2; f++) bs[4 + f] = *(const bf16x8*)(s + f * 32 + q * 8);
    }
    bf16x8 bv[3][6];
    #pragma unroll
    for (int c = 0; c < 3; c++) {
        const unsigned short* a = agg_v_b + (size_t)node * 384 + c * 128;
        #pragma unroll
        for (int f = 0; f < 4; f++) bv[c][f] = *(const bf16x8*)(a + f * 32 + q * 8);
        const unsigned short* s = nv_t + (size_t)c * N_NODES * 64 + (size_t)node * 64;
        #pragma unroll
        for (int f = 0; f < 2; f++) bv[c][4 + f] = *(const bf16x8*)(s + f * 32 + q * 8);
    }
    f32x4 z4 = {0.f, 0.f, 0.f, 0.f};
    float gate[4][4];
    #pragma unroll
    for (int t = 0; t < 4; t++) {
        f32x4 c = z4;
        #pragma unroll
        for (int f = 0; f < 6; f++) {
            bf16x8 a = *(const bf16x8*)(As + (16 * (4 + t) + m) * 200 + f * 32 + q * 8);
            c = __builtin_amdgcn_mfma_f32_16x16x32_bf16(a, bs[f], c, 0, 0, 0);
        }
        #pragma unroll
        for (int r = 0; r < 4; r++) gate[t][r] = swishf(c[r]);
    }
    #pragma unroll
    for (int t = 0; t < 4; t++) {
        f32x4 c = z4;
        #pragma unroll
        for (int f = 0; f < 6; f++) {
            bf16x8 a = *(const bf16x8*)(As + (16 * t + m) * 200 + f * 32 + q * 8);
            c = __builtin_amdgcn_mfma_f32_16x16x32_bf16(a, bs[f], c, 0, 0, 0);
        }
        if (m < cnt) {
            size_t base = (size_t)node * 256 + 16 * t + 4 * q;
            if (f32) {
                float4 o4 = { swishf(c[0]), swishf(c[1]), swishf(c[2]), swishf(c[3]) };
                *(float4*)((float*)out + base) = o4;
            } else {
                uint2 o2;
                o2.x = f2bf_bits(swishf(c[0])) | ((unsigned)f2bf_bits(swishf(c[1])) << 16);
                o2.y = f2bf_bits(swishf(c[2])) | ((unsigned)f2bf_bits(swishf(c[3])) << 16);
                *(uint2*)((unsigned short*)out + base) = o2;
            }
        }
    }
    #pragma unroll
    for (int t = 0; t < 4; t++) {
        f32x4 c0 = z4, c1 = z4, c2 = z4;
        #pragma unroll
        for (int f = 0; f < 6; f++) {
            bf16x8 a = *(const bf16x8*)(Av + (16 * t + m) * 200 + f * 32 + q * 8);
            c0 = __builtin_amdgcn_mfma_f32_16x16x32_bf16(a, bv[0][f], c0, 0, 0, 0);
            c1 = __builtin_amdgcn_mfma_f32_16x16x32_bf16(a, bv[1][f], c1, 0, 0, 0);
            c2 = __builtin_amdgcn_mfma_f32_16x16x32_bf16(a, bv[2][f], c2, 0, 0, 0);
        }
        if (m < cnt) {
            #pragma unroll
            for (int r = 0; r < 4; r++) {
                float g = gate[t][r];
                int o = 16 * t + 4 * q + r;
                size_t base = (size_t)node * 256 + 64 + (size_t)o * 3;
                if (f32) {
                    ((float*)out)[base + 0] = c0[r] * g;
                    ((float*)out)[base + 1] = c1[r] * g;
                    ((float*)out)[base + 2] = c2[r] * g;
                } else {
                    ((__hip_bfloat16*)out)[base + 0] = __float2bfloat16(c0[r] * g);
                    ((__hip_bfloat16*)out)[base + 1] = __float2bfloat16(c1[r] * g);
                    ((__hip_bfloat16*)out)[base + 2] = __float2bfloat16(c2[r] * g);
                }
            }
        }
    }
}

extern "C" void kernel_launch(void* const* d_in, const int* in_sizes, int n_in,
                              void* d_out, int out_size, void* d_ws, size_t ws_size,
                              hipStream_t stream) {
    const void* vectors      = d_in[0];
    const void* node_scalars = d_in[1];
    const void* node_vectors = d_in[2];
    const int* node_specie   = (const int*)d_in[3];
    const int* senders       = (const int*)d_in[4];
    const int* receivers     = (const int*)d_in[5];
    const void* W_up_s       = d_in[6];
    const void* W_up_v       = d_in[7];
    const void* W_skip_s     = d_in[8];
    const void* W_skip_v     = d_in[9];
    const void* W_mlp1       = d_in[10];
    const void* W_mlp2       = d_in[11];
    const void* W_mlp3       = d_in[12];
    const void* W_down_s     = d_in[13];
    const void* W_down_v     = d_in[14];

    char* ws = (char*)d_ws;
    size_t off = 0;
    auto alloc = [&](size_t bytes) { void* p = ws + off; off += (bytes + 255) & ~(size_t)255; return p; };
    unsigned short* hbuf     = (unsigned short*)alloc((size_t)N_NODES * 256 * 2);
    unsigned short* ns_b     = (unsigned short*)alloc((size_t)N_NODES * 64 * 2);
    unsigned short* nv_t     = (unsigned short*)alloc((size_t)N_NODES * 192 * 2);
    unsigned short* agg_s_b  = (unsigned short*)alloc((size_t)N_NODES * 128 * 2);
    unsigned short* agg_v_b  = (unsigned short*)alloc((size_t)N_NODES * 384 * 2);
    unsigned short* mixp     = (unsigned short*)alloc((size_t)SEG_E * 256 * 2);   // 122.88 MB packed
    unsigned short* yq       = (unsigned short*)alloc((size_t)N_EDGES * 4 * 2);
    unsigned short* rbq      = (unsigned short*)alloc((size_t)N_EDGES * 8 * 2);   // 7.68 MB
    unsigned short* Wup_sq   = (unsigned short*)alloc((size_t)64 * 72 * 2);
    unsigned short* Wup_vq   = (unsigned short*)alloc((size_t)64 * 72 * 2);
    unsigned short* Wq_s     = (unsigned short*)alloc((size_t)5 * 128 * 200 * 2);
    unsigned short* Wq_v     = (unsigned short*)alloc((size_t)5 * 64 * 200 * 2);
    unsigned short* W2q      = (unsigned short*)alloc((size_t)64 * 72 * 2);
    unsigned short* W3q      = (unsigned short*)alloc((size_t)256 * 72 * 2);
    int* cnt        = (int*)alloc((size_t)(N_NODES + 8) * 4);
    int* cnt5       = cnt + N_NODES;
    int* offs       = (int*)alloc((size_t)(N_NODES + 1) * 4);
    int* cursor     = (int*)alloc((size_t)N_NODES * 4);
    int* sorted_snd = (int*)alloc((size_t)N_EDGES * 4);
    int* sorted_node= (int*)alloc((size_t)N_NODES * 4);
    int* sp_offs    = (int*)alloc(16 * 4);
    int* cursor5    = (int*)alloc(16 * 4);
    int* tile_info  = (int*)alloc(16 * 4);
    int* partials   = (int*)alloc((size_t)(SCAN_BLOCKS + 1) * 4);
    int* pscan      = (int*)alloc((size_t)(SCAN_BLOCKS + 1) * 4);
    int* flag       = (int*)alloc(4);

    detect_kernel<<<dim3(1), dim3(64), 0, stream>>>((const unsigned short*)W_up_s, flag);
    (void)hipMemsetAsync(cnt, 0, (size_t)(N_NODES + 8) * 4, stream);

    wprep_kernel<<<dim3(64), dim3(256), 0, stream>>>(
        W_up_s, W_up_v, W_skip_s, W_skip_v, W_down_s, W_down_v, W_mlp2, W_mlp3,
        Wup_sq, Wup_vq, Wq_s, Wq_v, W2q, W3q, flag);

    hist_kernel<<<dim3(1875), dim3(256), 0, stream>>>(receivers, cnt);
    partial_kernel<<<dim3(SCAN_BLOCKS), dim3(256), 0, stream>>>(cnt, partials);
    scanp_kernel<<<dim3(1), dim3(256), 0, stream>>>(partials, pscan);
    offs_kernel<<<dim3(SCAN_BLOCKS), dim3(256), 0, stream>>>(cnt, pscan, offs, cursor);
    scatter_kernel<<<dim3(1875), dim3(256), 0, stream>>>(receivers, senders, vectors,
                                                         cursor, sorted_snd, yq, rbq, flag);

    hist5_kernel<<<dim3(157), dim3(256), 0, stream>>>(node_specie, cnt5);
    scan5_kernel<<<dim3(1), dim3(64), 0, stream>>>(cnt5, sp_offs, cursor5, tile_info);
    scatter5_kernel<<<dim3(157), dim3(256), 0, stream>>>(node_specie, cursor5, sorted_node);

    // 625 blocks * 4 waves * 16 nodes = 40000
    node_up_kernel<<<dim3(625), dim3(256), 0, stream>>>(
        node_scalars, node_vectors, Wup_sq, Wup_vq, hbuf, ns_b, nv_t, flag);

    const int MLP_BLOCKS = (SEG_TILES + 8 * TPW - 1) / (8 * TPW);   // 469
    for (int s = 0; s < SEG; s++) {
        int p_lo = s * SEG_E;
        mlp_kernel<<<dim3(MLP_BLOCKS), dim3(512), 0, stream>>>(
            rbq, W_mlp1, W2q, W3q, mixp, p_lo, flag);
        agg_kernel<<<dim3(10000), dim3(256), 0, stream>>>(
            hbuf, sorted_snd, mixp, yq, offs, agg_s_b, agg_v_b, p_lo, p_lo + SEG_E);
    }

    node_final_kernel<<<dim3(640), dim3(256), 0, stream>>>(
        Wq_s, Wq_v, ns_b, nv_t, agg_s_b, agg_v_b,
        sorted_node, sp_offs, tile_info, d_out, flag);
}